// Round 25
// baseline (459.211 us; speedup 1.0000x reference)
//
#include <hip/hip_runtime.h>

#define HH 128
#define WW 128
#define HW (HH * WW)

typedef __bf16 bf16;
typedef bf16 bf16x4 __attribute__((ext_vector_type(4)));
typedef bf16 bf16x8 __attribute__((ext_vector_type(8)));
typedef float f32x4 __attribute__((ext_vector_type(4)));

__device__ __forceinline__ float hsig(float x) {
    return fminf(fmaxf(fmaf(0.2f, x, 0.5f), 0.f), 1.f);
}
__device__ __forceinline__ float ftanh(float x) {
    const float u = __expf(2.f * fminf(x, 40.f));
    return (u - 1.f) * __builtin_amdgcn_rcpf(u + 1.f);
}
__device__ __forceinline__ void gload16(const void* g, void* l) {
    __builtin_amdgcn_global_load_lds(
        (const __attribute__((address_space(1))) void*)g,
        (__attribute__((address_space(3))) void*)l, 16, 0, 0);
}

// ---- one-time weight prep: fp32 [tap][ci][cout] -> bf16 Wt[l][tap][cout][ci64]
__global__ void prep_weights(const float* __restrict__ Wx0, const float* __restrict__ Wh0,
                             const float* __restrict__ Wx1, const float* __restrict__ Wh1,
                             const float* __restrict__ Wx2, const float* __restrict__ Wh2,
                             const float* __restrict__ Wx3, const float* __restrict__ Wh3,
                             bf16* __restrict__ Wt)
{
    int idx = blockIdx.x * 256 + threadIdx.x;      // 4*9*128*64 = 294912
    if (idx >= 4 * 9 * 128 * 64) return;
    const int l = idx / 73728;
    int r = idx - l * 73728;
    const int tap = r / (128 * 64);
    r -= tap * 128 * 64;
    const int co = r >> 6;
    const int ci = r & 63;
    const int CX = (l == 0) ? 16 : 32;
    const float* Wx = (l == 0) ? Wx0 : (l == 1) ? Wx1 : (l == 2) ? Wx2 : Wx3;
    const float* Wh = (l == 0) ? Wh0 : (l == 1) ? Wh1 : (l == 2) ? Wh2 : Wh3;
    float v = 0.f;
    if (ci < 32) { if (ci < CX) v = Wx[((size_t)tap * CX + ci) * 128 + co]; }
    else          v = Wh[((size_t)tap * 32 + (ci - 32)) * 128 + co];
    Wt[(size_t)l * 73728 + ((size_t)tap * 128 + co) * 64 + ci] = (bf16)v;
}

// ---- one-time: x fp32 -> bf16, and zero-page init ----
// Covers ALL 4*8*HW*16 = 8,388,608 elems -> 1,048,576 threads -> 4096 blocks.
__global__ void prep_x_zp(const float* __restrict__ x, bf16* __restrict__ xbf,
                          float* __restrict__ zp)
{
    const int idx = blockIdx.x * 256 + threadIdx.x;
    if (idx < 64) zp[idx] = 0.f;
    const int base = idx * 8;
    if (base < 4 * 8 * HW * 16) {
        const f32x4 a = *(const f32x4*)(x + base);
        const f32x4 b = *(const f32x4*)(x + base + 4);
        bf16x8 w;
        w[0] = (bf16)a.x; w[1] = (bf16)a.y; w[2] = (bf16)a.z; w[3] = (bf16)a.w;
        w[4] = (bf16)b.x; w[5] = (bf16)b.y; w[6] = (bf16)b.z; w[7] = (bf16)b.w;
        *(bf16x8*)(xbf + base) = w;
    }
}

// Diagonal-wavefront ConvLSTM stage. M=128/wave, swapped-operand C^T,
// vectorized epilogue. Staging = 12 x global_load_lds (pure 16B DMA copies,
// per-lane global src, wave-uniform LDS dest + lane*16) into [c8][pix] LDS.
// Inputs pre-transformed: x pre-bf16; r2 = relu(h1) by l1; r3 = relu(h2+h0)
// by l2. OOB/pad/t=0 lanes read a zero-page. DMAs issued FIRST (longest pole).
__global__ __launch_bounds__(128, 2)
void lstm_stage(const bf16* __restrict__ xbf,
                const bf16* __restrict__ Wt,
                const float* __restrict__ b0, const float* __restrict__ b1,
                const float* __restrict__ b2, const float* __restrict__ b3,
                bf16* __restrict__ h0, bf16* __restrict__ h1,
                bf16* __restrict__ h2, bf16* __restrict__ h3,
                bf16* __restrict__ r2, bf16* __restrict__ r3,
                float* __restrict__ cbase,
                const float* __restrict__ zp,
                float* __restrict__ outf,
                const int d, const int lmin)
{
    __shared__ bf16 sact[12288];       // 1536 items x 8 bf16 (16B); [c8][pix]

    const int tid = threadIdx.x;
    const int bx = blockIdx.x, by = blockIdx.y;
    const int s  = blockIdx.z >> 2, bb = blockIdx.z & 3;
    const int l  = lmin + s;
    const int t  = d - l;

    const size_t S = (size_t)4 * HW * 32;
    bf16* hlbase = (l == 0) ? h0 : (l == 1) ? h1 : (l == 2) ? h2 : h3;
    bf16*       hcur = hlbase + (size_t)((l == 0) ? (t & 3) : (t & 1)) * S;
    const bf16* hprv = hlbase + (size_t)((l == 0) ? ((t + 3) & 3) : ((t + 1) & 1)) * S;
    const float* bias = (l == 0) ? b0 : (l == 1) ? b1 : (l == 2) ? b2 : b3;
    float* cst = cbase + (size_t)l * S;

    // block-uniform input descriptor (all inputs pre-transformed, pure copy)
    const bf16* inbase; int inchunks, instride;
    if (l == 0)      { inbase = xbf + (size_t)(bb * 8 + t) * HW * 16; inchunks = 2; instride = 16; }
    else if (l == 1) { inbase = h0 + (size_t)(t & 3) * S + (size_t)bb * HW * 32; inchunks = 4; instride = 32; }
    else if (l == 2) { inbase = r2 + (size_t)(t & 1) * S + (size_t)bb * HW * 32; inchunks = 4; instride = 32; }
    else             { inbase = r3 + (size_t)(t & 1) * S + (size_t)bb * HW * 32; inchunks = 4; instride = 32; }
    const bf16* hp = hprv + (size_t)bb * HW * 32;
    const bool hval = (t > 0);

    const int lane = tid & 63;
    const int p    = tid >> 6;        // wave parity: cout group
    const int col  = lane & 15;       // act pixel-x / output pixel-x
    const int krow = lane >> 4;       // k-octet / cout sub-block
    const int f0 = p * 16 + krow * 4; // 4 consecutive filters per thread

    const size_t pb0 = (((size_t)bb * HH + by * 8) * WW + bx * 16 + col) * 32 + f0;
    const bf16* __restrict__ wb0 = Wt + (size_t)l * 73728 + (size_t)(p * 16 + col) * 64 + krow * 8;

    // ---- staging FIRST: 12 x global_load_lds (longest-latency pole) ----
    // item = c8*180 + pix (pix = hy*18+hx in 10x18 halo); lane item = k*128+tid.
    auto item_src = [&](int item) -> const bf16* {
        const unsigned c8  = (unsigned)item / 180u;
        const unsigned pix = (unsigned)item - c8 * 180u;
        const int hy = (int)(pix / 18u);
        const int hx = (int)pix - hy * 18;
        const int sy = by * 8 - 1 + hy, sx = bx * 16 - 1 + hx;
        const bool inb = ((unsigned)sy < HH) && ((unsigned)sx < WW) && (c8 < 8u);
        const int poff = sy * WW + sx;
        const bf16* src;
        if (c8 < 4u) src = ((int)c8 < inchunks)
                         ? inbase + (size_t)poff * instride + c8 * 8
                         : (const bf16*)zp;
        else         src = (hval && c8 < 8u)
                         ? hp + (size_t)poff * 32 + (c8 - 4u) * 8
                         : (const bf16*)zp;
        return inb ? src : (const bf16*)zp;
    };
    #pragma unroll
    for (int k = 0; k < 12; ++k) {
        const bf16* src = item_src(k * 128 + tid);
        gload16(src, &sact[(size_t)(k * 128 + (tid >> 6) * 64) * 8]);
    }

    bf16x8 B0[2][4], B1[2][4];

#define LOAD_B(Bbuf, tap) do {                                               \
        const bf16* wt_ = wb0 + (size_t)(tap) * 8192;                        \
        _Pragma("unroll")                                                    \
        for (int q_ = 0; q_ < 4; ++q_) {                                     \
            Bbuf[0][q_] = *(const bf16x8*)(wt_ + q_ * 2048);                 \
            Bbuf[1][q_] = *(const bf16x8*)(wt_ + q_ * 2048 + 32);            \
        }                                                                    \
    } while (0)

    // ---- tap-0 weights + c prefetch hide under the DMA queue ----
    LOAD_B(B0, 0);
    f32x4 cpre4[8];
    #pragma unroll
    for (int i = 0; i < 8; ++i) cpre4[i] = (f32x4){0.f, 0.f, 0.f, 0.f};
    if (t > 0) {
        #pragma unroll
        for (int mt = 0; mt < 8; ++mt)
            cpre4[mt] = *(const f32x4*)(cst + pb0 + (size_t)mt * WW * 32);
    }
    __syncthreads();   // compiler drains vmcnt (DMA queue) before barrier

    // bias seeds + acc init
    f32x4 bseed4[4];
    #pragma unroll
    for (int q = 0; q < 4; ++q)
        bseed4[q] = *(const f32x4*)(bias + (p + 2 * q) * 16 + krow * 4);
    f32x4 acc2[8][4];
    #pragma unroll
    for (int q = 0; q < 4; ++q)
        #pragma unroll
        for (int mt = 0; mt < 8; ++mt) acc2[mt][q] = bseed4[q];

    // A cell (c8, pix) at elems c8*1440 + pix*8; Aa: c8=krow, Ab: c8=krow+4.
#define MFMA_TAP(Bbuf, tap) do {                                             \
        const int dy_ = (tap) / 3, dx_ = (tap) - dy_ * 3;                    \
        const int o0_ = krow * 1440 + (dy_ * 18 + dx_ + col) * 8;            \
        _Pragma("unroll")                                                    \
        for (int mt_ = 0; mt_ < 8; ++mt_) {                                  \
            const bf16x8 Aa = *(const bf16x8*)(&sact[o0_ + mt_ * 144]);       \
            const bf16x8 Ab = *(const bf16x8*)(&sact[o0_ + 5760 + mt_ * 144]);\
            __builtin_amdgcn_s_setprio(1);                                   \
            _Pragma("unroll")                                                \
            for (int q_ = 0; q_ < 4; ++q_)                                   \
                acc2[mt_][q_] = __builtin_amdgcn_mfma_f32_16x16x32_bf16(     \
                    Bbuf[0][q_], Aa, acc2[mt_][q_], 0, 0, 0);                \
            _Pragma("unroll")                                                \
            for (int q_ = 0; q_ < 4; ++q_)                                   \
                acc2[mt_][q_] = __builtin_amdgcn_mfma_f32_16x16x32_bf16(     \
                    Bbuf[1][q_], Ab, acc2[mt_][q_], 0, 0, 0);                \
            __builtin_amdgcn_s_setprio(0);                                   \
        }                                                                    \
    } while (0)

    #pragma unroll 1
    for (int k = 0; k < 4; ++k) {
        const int t1 = 2 * k + 1, t2 = 2 * k + 2;
        LOAD_B(B1, t1);
        MFMA_TAP(B0, 2 * k);
        LOAD_B(B0, t2);
        MFMA_TAP(B1, t1);
    }
    MFMA_TAP(B0, 8);   // tap 8

#undef LOAD_B
#undef MFMA_TAP

    // ---- epilogue: vectorized; producers pre-transform for consumers ----
    bf16x4 h0r[8];
    if (l == 2) {
        const bf16* h0t = h0 + (size_t)(t & 3) * S;
        #pragma unroll
        for (int mt = 0; mt < 8; ++mt)
            h0r[mt] = *(const bf16x4*)(h0t + pb0 + (size_t)mt * WW * 32);
    }
    bf16* r2w = r2 + (size_t)(t & 1) * S;
    bf16* r3w = r3 + (size_t)(t & 1) * S;

    #pragma unroll
    for (int mt = 0; mt < 8; ++mt) {
        const size_t pb = pb0 + (size_t)mt * WW * 32;
        f32x4 cn4, hn4;
        #pragma unroll
        for (int j = 0; j < 4; ++j) {
            const float zi = acc2[mt][0][j];
            const float zf = acc2[mt][1][j];
            const float zg = acc2[mt][2][j];
            const float zo = acc2[mt][3][j];
            const float ig = hsig(zi), fg = hsig(zf);
            const float gg = ftanh(zg), og = hsig(zo);
            const float cn = fmaf(fg, cpre4[mt][j], ig * gg);
            cn4[j] = cn;
            hn4[j] = og * ftanh(cn);
        }
        if (t != 7) *(f32x4*)(cst + pb) = cn4;        // c(8) never read
        if (l == 3 && t == 7) {
            *(f32x4*)(outf + pb) = hn4;
        } else {
            bf16x4 hv;
            #pragma unroll
            for (int j = 0; j < 4; ++j) hv[j] = (bf16)hn4[j];
            *(bf16x4*)(hcur + pb) = hv;
            if (l == 1) {                 // r2 = relu(h1), exact in bf16
                bf16x4 rv;
                #pragma unroll
                for (int j = 0; j < 4; ++j)
                    rv[j] = ((float)hv[j] > 0.f) ? hv[j] : (bf16)0.f;
                *(bf16x4*)(r2w + pb) = rv;
            } else if (l == 2) {          // r3 = relu(h2 + h0[t])
                bf16x4 rv;
                #pragma unroll
                for (int j = 0; j < 4; ++j)
                    rv[j] = (bf16)fmaxf((float)hv[j] + (float)h0r[mt][j], 0.f);
                *(bf16x4*)(r3w + pb) = rv;
            }
        }
    }
}

extern "C" void kernel_launch(void* const* d_in, const int* in_sizes, int n_in,
                              void* d_out, int out_size, void* d_ws, size_t ws_size,
                              hipStream_t stream) {
    const float* x = (const float*)d_in[0];
    const float* Wx[4] = {(const float*)d_in[1], (const float*)d_in[4],
                          (const float*)d_in[7], (const float*)d_in[10]};
    const float* Wh[4] = {(const float*)d_in[2], (const float*)d_in[5],
                          (const float*)d_in[8], (const float*)d_in[11]};
    const float* bs[4] = {(const float*)d_in[3], (const float*)d_in[6],
                          (const float*)d_in[9], (const float*)d_in[12]};
    float* out = (float*)d_out;

    const size_t S  = (size_t)4 * HW * 32;        // one [B,H,W,32] image (elems)
    const size_t WT = (size_t)4 * 73728;          // weights (bf16 elems)

    float* zp = (float*)d_ws;                     // 64-float zero page
    bf16* wt  = (bf16*)(zp + 64);
    bf16* xbf = wt + WT;                          // 4S elems (B,T,H,W,16)
    bf16* h0  = xbf + 4 * S;                      // 4-deep ring
    bf16* h1  = h0 + 4 * S;                       // 2-deep rings
    bf16* h2  = h1 + 2 * S;
    bf16* h3  = h2 + 2 * S;
    bf16* r2  = h3 + 2 * S;                       // relu(h1), 2-deep
    bf16* r3  = r2 + 2 * S;                       // relu(h2+h0), 2-deep
    float* cb = (float*)(r3 + 2 * S);             // 4 x S fp32 c-state

    prep_weights<<<1152, 256, 0, stream>>>(Wx[0], Wh[0], Wx[1], Wh[1],
                                           Wx[2], Wh[2], Wx[3], Wh[3], wt);
    prep_x_zp<<<4096, 256, 0, stream>>>(x, xbf, zp);

    // Diagonal wavefront: d = t + l, stages on one diagonal are independent.
    for (int d = 0; d <= 10; ++d) {
        const int lmin = (d > 7) ? (d - 7) : 0;
        const int lmax = (d < 3) ? d : 3;
        const int nst  = lmax - lmin + 1;
        dim3 grid(WW / 16, HH / 8, nst * 4);
        lstm_stage<<<grid, dim3(128), 0, stream>>>(
            xbf, wt, bs[0], bs[1], bs[2], bs[3],
            h0, h1, h2, h3, r2, r3, cb, zp, out, d, lmin);
    }
}